// Round 2
// baseline (2137.861 us; speedup 1.0000x reference)
//
#include <hip/hip_runtime.h>
#include <cstdint>
#include <cstddef>

#define B_ 2048
#define N_ 62
#define FIN_ 128
#define HID_ 512
#define HEADS_ 8
#define FOUT_ 64
#define LAYERS_ 3
#define M_ (B_*N_)           // 126976
#define CH_ 512              // graphs per chunk
#define CHROWS_ (CH_*N_)     // 31744
#define NCHUNK_ (B_/CH_)     // 4

typedef __bf16 bf16x8 __attribute__((ext_vector_type(8)));
typedef float  f32x4  __attribute__((ext_vector_type(4)));
typedef unsigned short u16;

static __device__ __forceinline__ u16 f2bf(float f) {
    union { float f; uint32_t u; } v; v.f = f;
    uint32_t u = v.u;
    return (u16)((u + 0x7fffu + ((u >> 16) & 1u)) >> 16);
}
static __device__ __forceinline__ float bf2f(u16 s) {
    union { uint32_t u; float f; } v; v.u = ((uint32_t)s) << 16;
    return v.f;
}

// ---------------------------------------------------------------------------
// xb[b,n,f] = BN(x) cast to bf16.  One float4 group per thread.
// ---------------------------------------------------------------------------
__global__ __launch_bounds__(256) void bn_cast(
    const float* __restrict__ x, const float* __restrict__ bng,
    const float* __restrict__ bnb, const float* __restrict__ bnm,
    const float* __restrict__ bnv, u16* __restrict__ xb)
{
    int g = blockIdx.x * 256 + threadIdx.x;
    if (g >= M_ * (FIN_ / 4)) return;
    int row = g >> 5;          // FIN_/4 = 32 groups per row
    int n = row % N_;
    float s = bng[n] * rsqrtf(bnv[n] + 1e-5f);
    float sh = bnb[n] - bnm[n] * s;
    float4 v = ((const float4*)x)[g];
    ushort4 o;
    o.x = f2bf(v.x * s + sh);
    o.y = f2bf(v.y * s + sh);
    o.z = f2bf(v.z * s + sh);
    o.w = f2bf(v.w * s + sh);
    ((ushort4*)xb)[g] = o;
}

// ---------------------------------------------------------------------------
// Pack transposed bf16 weights:
//  wmlp_t[n][k] = W_mlp[k][n]          (512 x 128)
//  wgat_t[l][n][k] = W_gat[l][n>>6][k][n&63]   (3 x 512 x 512)
// ---------------------------------------------------------------------------
__global__ __launch_bounds__(256) void repack_w(
    const float* __restrict__ Wm, const float* __restrict__ Wg,
    u16* __restrict__ wmlp_t, u16* __restrict__ wgat_t)
{
    int idx = blockIdx.x * 256 + threadIdx.x;
    const int T1 = HID_ * FIN_;
    const int T2 = LAYERS_ * HID_ * HID_;
    if (idx < T1) {
        int n = idx / FIN_, k = idx % FIN_;
        wmlp_t[idx] = f2bf(Wm[k * HID_ + n]);
    } else if (idx < T1 + T2) {
        int j = idx - T1;
        int l = j / (HID_ * HID_);
        int r = j % (HID_ * HID_);
        int n = r / HID_, k = r % HID_;
        wgat_t[j] = f2bf(Wg[(((size_t)(l * HEADS_ + (n >> 6))) * HID_ + k) * FOUT_ + (n & 63)]);
    }
}

// ---------------------------------------------------------------------------
// bf16 MFMA GEMM: C[rows,512] = A[rows,K] @ Bt[512,K]^T (+bias), bf16 out.
// 128x128 block, 4 waves, each wave 32x128 (2x8 grid of 16x16x32 MFMA).
// LDS tiles padded to stride 40 bf16 (conflict-free ds_read_b128).
// rows % 128 == 0, K % 32 == 0.
// ---------------------------------------------------------------------------
__global__ __launch_bounds__(256) void gemm_mfma(
    const u16* __restrict__ A, const u16* __restrict__ Bt,
    const float* __restrict__ bias, u16* __restrict__ C,
    int K, int lda)
{
    __shared__ u16 As[128 * 40];
    __shared__ u16 Bs[128 * 40];
    const int tid = threadIdx.x;
    const int wave = tid >> 6, lane = tid & 63;
    const int lr = lane & 15, lq = lane >> 4;
    const int bx = blockIdx.x & 3;            // Nn=512 -> 4 col blocks
    const int by = blockIdx.x >> 2;
    const int row0 = by << 7, col0 = bx << 7;

    const int srow = tid >> 2, skq = tid & 3;  // staging: row, 8-elt slot

    f32x4 acc[2][8];
#pragma unroll
    for (int mt = 0; mt < 2; mt++)
#pragma unroll
        for (int nt = 0; nt < 8; nt++) acc[mt][nt] = (f32x4){0.f, 0.f, 0.f, 0.f};

    const int arow0 = wave * 32 + lr;
    for (int k0 = 0; k0 < K; k0 += 32) {
        uint4 av[2], bv[2];
#pragma unroll
        for (int it = 0; it < 2; it++) {
            int row = srow + it * 64;
            av[it] = *(const uint4*)(A + (size_t)(row0 + row) * lda + k0 + skq * 8);
            bv[it] = *(const uint4*)(Bt + (size_t)(col0 + row) * K + k0 + skq * 8);
        }
        __syncthreads();
#pragma unroll
        for (int it = 0; it < 2; it++) {
            int row = srow + it * 64;
            *(uint4*)&As[row * 40 + skq * 8] = av[it];
            *(uint4*)&Bs[row * 40 + skq * 8] = bv[it];
        }
        __syncthreads();

        bf16x8 afrag[2], bfrag[8];
        afrag[0] = *(const bf16x8*)&As[(arow0) * 40 + lq * 8];
        afrag[1] = *(const bf16x8*)&As[(arow0 + 16) * 40 + lq * 8];
#pragma unroll
        for (int nt = 0; nt < 8; nt++)
            bfrag[nt] = *(const bf16x8*)&Bs[(nt * 16 + lr) * 40 + lq * 8];
#pragma unroll
        for (int mt = 0; mt < 2; mt++)
#pragma unroll
            for (int nt = 0; nt < 8; nt++)
                acc[mt][nt] = __builtin_amdgcn_mfma_f32_16x16x32_bf16(
                    afrag[mt], bfrag[nt], acc[mt][nt], 0, 0, 0);
    }

    float bl[8];
#pragma unroll
    for (int nt = 0; nt < 8; nt++)
        bl[nt] = bias ? bias[col0 + nt * 16 + lr] : 0.f;

#pragma unroll
    for (int mt = 0; mt < 2; mt++) {
#pragma unroll
        for (int nt = 0; nt < 8; nt++) {
            int col = col0 + nt * 16 + lr;
#pragma unroll
            for (int r = 0; r < 4; r++) {
                int row = row0 + wave * 32 + mt * 16 + lq * 4 + r;
                C[(size_t)row * HID_ + col] = f2bf(acc[mt][nt][r] + bl[nt]);
            }
        }
    }
}

// ---------------------------------------------------------------------------
// Per-(graph, head) GAT attention; bf16 in/out, fp32 math.
// hbuf rows are chunk-local; adj/hx pointers pre-offset to the chunk.
// ---------------------------------------------------------------------------
__global__ __launch_bounds__(256) void gat_attn(
    const u16* __restrict__ hbuf, const int* __restrict__ adj,
    const float* __restrict__ a_gat_l, u16* __restrict__ hx)
{
    __shared__ float hs[N_ * 64];
    __shared__ float e[64 * 64];
    __shared__ float f1[64], f2[64], cmax[64], crcp[64], a12[128];
    const int tid = threadIdx.x;
    const int b = blockIdx.x >> 3;
    const int head = blockIdx.x & 7;

    const u16* hsrc = hbuf + ((size_t)b * N_) * HID_ + head * FOUT_;
    for (int idx = tid; idx < N_ * 8; idx += 256) {
        int r = idx >> 3, q = idx & 7;
        uint4 v = *(const uint4*)(hsrc + (size_t)r * HID_ + q * 8);
        const u16* pu = (const u16*)&v;
#pragma unroll
        for (int t = 0; t < 8; t++) hs[r * 64 + q * 8 + t] = bf2f(pu[t]);
    }
    if (tid < 128) a12[tid] = a_gat_l[head * 128 + tid];
    __syncthreads();

    if (tid < N_) {
        float p1 = 0.f, p2 = 0.f;
#pragma unroll
        for (int kk = 0; kk < 64; kk++) {
            int k = (kk + tid) & 63;
            float hv = hs[tid * 64 + k];
            p1 += hv * a12[k];
            p2 += hv * a12[64 + k];
        }
        f1[tid] = p1;
        f2[tid] = p2;
    }
    __syncthreads();

    const int* adjb = adj + (size_t)b * N_ * N_;
    for (int idx = tid; idx < N_ * N_; idx += 256) {
        int i = idx / N_, j = idx % N_;
        float v = f2[i] + f1[j];
        v = v > 0.f ? v : 0.2f * v;
        if (adjb[idx] <= 0) v = -9e15f;
        e[i * 64 + j] = v;
    }
    __syncthreads();

    if (tid < N_) {   // column softmax (reference softmax axis = i)
        int j = tid;
        float m = -3.0e38f;
        for (int i = 0; i < N_; i++) m = fmaxf(m, e[i * 64 + j]);
        float s = 0.f;
        for (int i = 0; i < N_; i++) s += __expf(e[i * 64 + j] - m);
        cmax[j] = m;
        crcp[j] = 1.f / s;
    }
    __syncthreads();
    for (int idx = tid; idx < N_ * N_; idx += 256) {
        int i = idx / N_, j = idx % N_;
        e[i * 64 + j] = __expf(e[i * 64 + j] - cmax[j]) * crcp[j];
    }
    __syncthreads();

    const int tx = tid & 15, ty = tid >> 4;
    float acc[4][4];
#pragma unroll
    for (int ii = 0; ii < 4; ii++)
#pragma unroll
        for (int c = 0; c < 4; c++) acc[ii][c] = 0.f;

    for (int j = 0; j < N_; j++) {
        float4 hv = *(const float4*)&hs[j * 64 + (tx << 2)];
#pragma unroll
        for (int ii = 0; ii < 4; ii++) {
            int i = (ty << 2) + ii;
            float av = (i < N_) ? e[i * 64 + j] : 0.f;
            acc[ii][0] += av * hv.x;
            acc[ii][1] += av * hv.y;
            acc[ii][2] += av * hv.z;
            acc[ii][3] += av * hv.w;
        }
    }

    u16* outp = hx + ((size_t)b * N_) * HID_ + head * FOUT_ + (tx << 2);
#pragma unroll
    for (int ii = 0; ii < 4; ii++) {
        int i = (ty << 2) + ii;
        if (i < N_) {
            ushort4 o;
            float v0 = acc[ii][0], v1 = acc[ii][1], v2 = acc[ii][2], v3 = acc[ii][3];
            o.x = f2bf(v0 > 0.f ? v0 : __expf(v0) - 1.f);
            o.y = f2bf(v1 > 0.f ? v1 : __expf(v1) - 1.f);
            o.z = f2bf(v2 > 0.f ? v2 : __expf(v2) - 1.f);
            o.w = f2bf(v3 > 0.f ? v3 : __expf(v3) - 1.f);
            *(ushort4*)(outp + (size_t)i * HID_) = o;
        }
    }
}

// ---------------------------------------------------------------------------
// pooled[b,:] = sum_n hx[b,n,:]; logits = pooled @ W_out + b_out; log_softmax
// ---------------------------------------------------------------------------
__global__ __launch_bounds__(256) void pool_out(
    const u16* __restrict__ hx, const float* __restrict__ Wout,
    const float* __restrict__ bout, float* __restrict__ out)
{
    __shared__ float pooled[HID_];
    __shared__ float lg[3];
    const int tid = threadIdx.x;
    const int b = blockIdx.x;
    const u16* hb = hx + (size_t)b * N_ * HID_;
    for (int f = tid; f < HID_; f += 256) {
        float s = 0.f;
        for (int n = 0; n < N_; n++) s += bf2f(hb[n * HID_ + f]);
        pooled[f] = s;
    }
    __syncthreads();
    if (tid < 192) {
        int c = tid >> 6, lane = tid & 63;
        float p = 0.f;
        for (int k = lane; k < HID_; k += 64) p += pooled[k] * Wout[k * 3 + c];
        for (int off = 32; off > 0; off >>= 1) p += __shfl_down(p, off, 64);
        if (lane == 0) lg[c] = p + bout[c];
    }
    __syncthreads();
    if (tid == 0) {
        float l0 = lg[0], l1 = lg[1], l2 = lg[2];
        float m = fmaxf(l0, fmaxf(l1, l2));
        float s = __expf(l0 - m) + __expf(l1 - m) + __expf(l2 - m);
        float ls = m + logf(s);
        out[b * 3 + 0] = l0 - ls;
        out[b * 3 + 1] = l1 - ls;
        out[b * 3 + 2] = l2 - ls;
    }
}

// ---------------------------------------------------------------------------
extern "C" void kernel_launch(void* const* d_in, const int* in_sizes, int n_in,
                              void* d_out, int out_size, void* d_ws, size_t ws_size,
                              hipStream_t stream)
{
    const float* x   = (const float*)d_in[0];
    const int*   adj = (const int*)d_in[1];
    const float* bng = (const float*)d_in[2];
    const float* bnb = (const float*)d_in[3];
    const float* bnm = (const float*)d_in[4];
    const float* bnv = (const float*)d_in[5];
    const float* Wm  = (const float*)d_in[6];
    const float* bm  = (const float*)d_in[7];
    const float* Wg  = (const float*)d_in[8];
    const float* ag  = (const float*)d_in[9];
    const float* Wo  = (const float*)d_in[10];
    const float* bo  = (const float*)d_in[11];
    float* out = (float*)d_out;

    // ws layout (u16 elements): xb | hx | hbuf(chunk) | wmlp_t | wgat_t
    u16* xb     = (u16*)d_ws;
    u16* hx     = xb + (size_t)M_ * FIN_;
    u16* hbuf   = hx + (size_t)M_ * HID_;
    u16* wmlp_t = hbuf + (size_t)CHROWS_ * HID_;
    u16* wgat_t = wmlp_t + (size_t)HID_ * FIN_;

    bn_cast<<<(M_ * (FIN_ / 4) + 255) / 256, 256, 0, stream>>>(x, bng, bnb, bnm, bnv, xb);

    int rep_total = HID_ * FIN_ + LAYERS_ * HID_ * HID_;
    repack_w<<<(rep_total + 255) / 256, 256, 0, stream>>>(Wm, Wg, wmlp_t, wgat_t);

    // MLP: hx = xb @ W_mlp + b_mlp   (full M)
    gemm_mfma<<<(M_ / 128) * 4, 256, 0, stream>>>(xb, wmlp_t, bm, hx, FIN_, FIN_);

    for (int l = 0; l < LAYERS_; l++) {
        const u16* wt = wgat_t + (size_t)l * HID_ * HID_;
        const float* agl = ag + (size_t)l * HEADS_ * 2 * FOUT_;
        for (int c = 0; c < NCHUNK_; c++) {
            u16* hxc = hx + (size_t)c * CHROWS_ * HID_;
            const int* adjc = adj + (size_t)c * CH_ * N_ * N_;
            gemm_mfma<<<(CHROWS_ / 128) * 4, 256, 0, stream>>>(
                hxc, wt, nullptr, hbuf, HID_, HID_);
            gat_attn<<<CH_ * HEADS_, 256, 0, stream>>>(hbuf, adjc, agl, hxc);
        }
    }
    pool_out<<<B_, 256, 0, stream>>>(hx, Wo, bo, out);
}

// Round 3
// 949.788 us; speedup vs baseline: 2.2509x; 2.2509x over previous
//
#include <hip/hip_runtime.h>
#include <cstdint>
#include <cstddef>

#define B_ 2048
#define N_ 62
#define FIN_ 128
#define HID_ 512
#define HEADS_ 8
#define FOUT_ 64
#define LAYERS_ 3
#define M_ (B_*N_)           // 126976

typedef __bf16 bf16x8 __attribute__((ext_vector_type(8)));
typedef float  f32x4  __attribute__((ext_vector_type(4)));
typedef unsigned short u16;

static __device__ __forceinline__ u16 f2bf(float f) {
    union { float f; uint32_t u; } v; v.f = f;
    uint32_t u = v.u;
    return (u16)((u + 0x7fffu + ((u >> 16) & 1u)) >> 16);
}
static __device__ __forceinline__ float bf2f(u16 s) {
    union { uint32_t u; float f; } v; v.u = ((uint32_t)s) << 16;
    return v.f;
}

// ---------------------------------------------------------------------------
// xb = BN(x) cast to bf16
// ---------------------------------------------------------------------------
__global__ __launch_bounds__(256) void bn_cast(
    const float* __restrict__ x, const float* __restrict__ bng,
    const float* __restrict__ bnb, const float* __restrict__ bnm,
    const float* __restrict__ bnv, u16* __restrict__ xb)
{
    int g = blockIdx.x * 256 + threadIdx.x;
    if (g >= M_ * (FIN_ / 4)) return;
    int row = g >> 5;
    int n = row % N_;
    float s = bng[n] * rsqrtf(bnv[n] + 1e-5f);
    float sh = bnb[n] - bnm[n] * s;
    float4 v = ((const float4*)x)[g];
    ushort4 o;
    o.x = f2bf(v.x * s + sh);
    o.y = f2bf(v.y * s + sh);
    o.z = f2bf(v.z * s + sh);
    o.w = f2bf(v.w * s + sh);
    ((ushort4*)xb)[g] = o;
}

// ---------------------------------------------------------------------------
// Pack transposed bf16 weights: wmlp_t[n][k]; wgat_t[l][n][k] (n = head*64+d)
// ---------------------------------------------------------------------------
__global__ __launch_bounds__(256) void repack_w(
    const float* __restrict__ Wm, const float* __restrict__ Wg,
    u16* __restrict__ wmlp_t, u16* __restrict__ wgat_t)
{
    int idx = blockIdx.x * 256 + threadIdx.x;
    const int T1 = HID_ * FIN_;
    const int T2 = LAYERS_ * HID_ * HID_;
    if (idx < T1) {
        int n = idx / FIN_, k = idx % FIN_;
        wmlp_t[idx] = f2bf(Wm[k * HID_ + n]);
    } else if (idx < T1 + T2) {
        int j = idx - T1;
        int l = j / (HID_ * HID_);
        int r = j % (HID_ * HID_);
        int n = r / HID_, k = r % HID_;
        wgat_t[j] = f2bf(Wg[(((size_t)(l * HEADS_ + (n >> 6))) * HID_ + k) * FOUT_ + (n & 63)]);
    }
}

// ---------------------------------------------------------------------------
// adjacency -> per-row 64-bit masks, one block per graph
// ---------------------------------------------------------------------------
__global__ __launch_bounds__(256) void build_masks(
    const int* __restrict__ adj, uint64_t* __restrict__ masks)
{
    __shared__ uint32_t m32[128];
    const int b = blockIdx.x, tid = threadIdx.x;
    if (tid < 128) m32[tid] = 0;
    __syncthreads();
    const int* a = adj + (size_t)b * N_ * N_;
    for (int idx = tid; idx < N_ * N_; idx += 256) {
        int i = idx / N_, j = idx % N_;
        if (a[idx] > 0) atomicOr(&m32[i * 2 + (j >> 5)], 1u << (j & 31));
    }
    __syncthreads();
    if (tid < 128) ((uint32_t*)(masks + (size_t)b * 64))[tid] = m32[tid];
}

// ---------------------------------------------------------------------------
// bf16 MFMA GEMM for the MLP: C[M,512] = A[M,128] @ Bt[512,128]^T + bias.
// Epilogue staged through LDS for coalesced uint4 stores (fixes the 2.4x
// HBM write amplification seen with scalar u16 stores).
// ---------------------------------------------------------------------------
#define CS_STRIDE 136
__global__ __launch_bounds__(256) void gemm_mfma(
    const u16* __restrict__ A, const u16* __restrict__ Bt,
    const float* __restrict__ bias, u16* __restrict__ C,
    int K, int lda)
{
    __shared__ u16 sh[4 * 32 * CS_STRIDE];   // 17408 u16; As/Bs alias front
    u16* As = sh;                // 128*40 = 5120
    u16* Bs = sh + 5120;         // 128*40 = 5120
    const int tid = threadIdx.x;
    const int wave = tid >> 6, lane = tid & 63;
    const int lr = lane & 15, lq = lane >> 4;
    const int bx = blockIdx.x & 3;
    const int by = blockIdx.x >> 2;
    const int row0 = by << 7, col0 = bx << 7;
    const int srow = tid >> 2, skq = tid & 3;

    f32x4 acc[2][8];
#pragma unroll
    for (int mt = 0; mt < 2; mt++)
#pragma unroll
        for (int nt = 0; nt < 8; nt++) acc[mt][nt] = (f32x4){0.f, 0.f, 0.f, 0.f};

    const int arow0 = wave * 32 + lr;
    for (int k0 = 0; k0 < K; k0 += 32) {
        uint4 av[2], bv[2];
#pragma unroll
        for (int it = 0; it < 2; it++) {
            int row = srow + it * 64;
            av[it] = *(const uint4*)(A + (size_t)(row0 + row) * lda + k0 + skq * 8);
            bv[it] = *(const uint4*)(Bt + (size_t)(col0 + row) * K + k0 + skq * 8);
        }
        __syncthreads();
#pragma unroll
        for (int it = 0; it < 2; it++) {
            int row = srow + it * 64;
            *(uint4*)&As[row * 40 + skq * 8] = av[it];
            *(uint4*)&Bs[row * 40 + skq * 8] = bv[it];
        }
        __syncthreads();

        bf16x8 afrag[2], bfrag[8];
        afrag[0] = *(const bf16x8*)&As[(arow0) * 40 + lq * 8];
        afrag[1] = *(const bf16x8*)&As[(arow0 + 16) * 40 + lq * 8];
#pragma unroll
        for (int nt = 0; nt < 8; nt++)
            bfrag[nt] = *(const bf16x8*)&Bs[(nt * 16 + lr) * 40 + lq * 8];
#pragma unroll
        for (int mt = 0; mt < 2; mt++)
#pragma unroll
            for (int nt = 0; nt < 8; nt++)
                acc[mt][nt] = __builtin_amdgcn_mfma_f32_16x16x32_bf16(
                    afrag[mt], bfrag[nt], acc[mt][nt], 0, 0, 0);
    }

    float bl[8];
#pragma unroll
    for (int nt = 0; nt < 8; nt++)
        bl[nt] = bias ? bias[col0 + nt * 16 + lr] : 0.f;

    __syncthreads();   // everyone done with As/Bs before aliasing as C-stage
    u16* cs = sh + wave * 32 * CS_STRIDE;
#pragma unroll
    for (int mt = 0; mt < 2; mt++)
#pragma unroll
        for (int nt = 0; nt < 8; nt++)
#pragma unroll
            for (int r = 0; r < 4; r++)
                cs[(mt * 16 + lq * 4 + r) * CS_STRIDE + nt * 16 + lr] =
                    f2bf(acc[mt][nt][r] + bl[nt]);
    __syncthreads();
    // cooperative coalesced store: 32 rows x 128 cols per wave
#pragma unroll
    for (int it = 0; it < 8; it++) {
        int linear = it * 64 + lane;
        int r = linear >> 4, q = linear & 15;
        uint4 v = *(const uint4*)&cs[r * CS_STRIDE + q * 8];
        *(uint4*)(C + (size_t)(row0 + wave * 32 + r) * HID_ + col0 + q * 8) = v;
    }
}

// ---------------------------------------------------------------------------
// Fused GAT layer: one block per graph, 8 waves (wave = head).
// Phase 1: stage hx[b] -> LDS; per-head projection via MFMA (W from L2).
// Phase 2: transpose h into LDS (hT[d][j]).
// Phase 3: f1/f2 + column-softmax stats in registers (shuffles).
// Phase 4: P-fragments built on the fly -> hp via MFMA -> ELU -> store.
// ---------------------------------------------------------------------------
#define S_IN 520     // u16 stride for hin/hout [64][520]
#define S_T  72      // u16 stride for hT [512][72]
__global__ __launch_bounds__(512, 4) void gat_layer(
    const u16* __restrict__ hx_in, u16* __restrict__ hx_out,
    const u16* __restrict__ Wt, const float* __restrict__ ag,
    const uint64_t* __restrict__ masks)
{
    __shared__ u16 buf[HID_ * S_T];          // 36864 u16 = 73728 B (union)
    __shared__ uint64_t msk[64];
    const int tid = threadIdx.x;
    const int b = blockIdx.x;
    const int wave = tid >> 6;               // head
    const int lane = tid & 63;
    const int lr = lane & 15, lq = lane >> 4;

    // ---- stage hin [62][512] + zero pad rows 62,63 ----
    const u16* src = hx_in + (size_t)b * N_ * HID_;
    for (int idx = tid; idx < N_ * 64; idx += 512) {
        int r = idx >> 6, q = idx & 63;
        *(uint4*)&buf[r * S_IN + q * 8] = *(const uint4*)(src + r * HID_ + q * 8);
    }
    for (int idx = tid; idx < 2 * 64; idx += 512) {
        int r = N_ + (idx >> 6), q = idx & 63;
        *(uint4*)&buf[r * S_IN + q * 8] = (uint4){0u, 0u, 0u, 0u};
    }
    if (tid < 64) msk[tid] = (tid < N_) ? masks[(size_t)b * 64 + tid] : 0ull;
    __syncthreads();

    // ---- per-head projection: h = hin @ W_head  (64x512 @ 512x64) ----
    f32x4 acc[4][4];
#pragma unroll
    for (int mt = 0; mt < 4; mt++)
#pragma unroll
        for (int nt = 0; nt < 4; nt++) acc[mt][nt] = (f32x4){0.f, 0.f, 0.f, 0.f};

    const u16* wp = Wt + (size_t)wave * 64 * HID_;   // head slice [64][512]
    for (int kt = 0; kt < 16; kt++) {
        int k0 = kt * 32;
        bf16x8 af[4];
#pragma unroll
        for (int mt = 0; mt < 4; mt++)
            af[mt] = *(const bf16x8*)&buf[(mt * 16 + lr) * S_IN + k0 + lq * 8];
#pragma unroll
        for (int nt = 0; nt < 4; nt++) {
            bf16x8 bfr = *(const bf16x8*)(wp + (size_t)(nt * 16 + lr) * HID_ + k0 + lq * 8);
#pragma unroll
            for (int mt = 0; mt < 4; mt++)
                acc[mt][nt] = __builtin_amdgcn_mfma_f32_16x16x32_bf16(
                    af[mt], bfr, acc[mt][nt], 0, 0, 0);
        }
    }
    __syncthreads();   // hin reads done

    // ---- transpose h into hT[d_global][j] ----
#pragma unroll
    for (int nt = 0; nt < 4; nt++)
#pragma unroll
        for (int mt = 0; mt < 4; mt++)
#pragma unroll
            for (int r = 0; r < 4; r++)
                buf[(wave * 64 + nt * 16 + lr) * S_T + mt * 16 + lq * 4 + r] =
                    f2bf(acc[mt][nt][r]);
    __syncthreads();

    // ---- f1/f2 (lane = node j) ----
    float p1 = 0.f, p2 = 0.f;
    {
        const float* a1 = ag + wave * 128;
#pragma unroll
        for (int d = 0; d < 64; d++) {
            float hv = bf2f(buf[(wave * 64 + d) * S_T + lane]);
            p1 += hv * a1[d];
            p2 += hv * a1[64 + d];
        }
        if (lane >= N_) { p1 = 0.f; p2 = 0.f; }
    }

    // ---- column softmax stats (lane = column j) ----
    float mj, rsj;
    {
        int j = lane;
        float m = -3.0e38f;
#pragma unroll
        for (int i = 0; i < N_; i++) {
            float f2i = __shfl(p2, i, 64);
            float v = f2i + p1;
            v = fmaxf(v, 0.2f * v);
            float e = ((msk[i] >> j) & 1ull) ? v : -9e15f;
            m = fmaxf(m, e);
        }
        float s = 0.f;
#pragma unroll
        for (int i = 0; i < N_; i++) {
            float f2i = __shfl(p2, i, 64);
            float v = f2i + p1;
            v = fmaxf(v, 0.2f * v);
            float e = ((msk[i] >> j) & 1ull) ? v : -9e15f;
            s += __expf(e - m);
        }
        mj = m;
        rsj = 1.f / s;
    }

    // ---- hp = P @ h via MFMA, P-fragments built on the fly ----
    f32x4 acc2[4][4];
#pragma unroll
    for (int mt = 0; mt < 4; mt++)
#pragma unroll
        for (int nt = 0; nt < 4; nt++) acc2[mt][nt] = (f32x4){0.f, 0.f, 0.f, 0.f};

#pragma unroll
    for (int kt = 0; kt < 2; kt++) {
        int j0 = kt * 32 + lq * 8;
        float f1t[8], mjt[8], rjt[8];
#pragma unroll
        for (int t = 0; t < 8; t++) {
            f1t[t] = __shfl(p1, j0 + t, 64);
            mjt[t] = __shfl(mj, j0 + t, 64);
            rjt[t] = __shfl(rsj, j0 + t, 64);
        }
        bf16x8 hb[4];
#pragma unroll
        for (int nt = 0; nt < 4; nt++)
            hb[nt] = *(const bf16x8*)&buf[(wave * 64 + nt * 16 + lr) * S_T + kt * 32 + lq * 8];
#pragma unroll
        for (int mt = 0; mt < 4; mt++) {
            int i = mt * 16 + lr;
            float f2i = __shfl(p2, i, 64);
            uint64_t mi = msk[i];
            bf16x8 pf;
#pragma unroll
            for (int t = 0; t < 8; t++) {
                int j = j0 + t;
                float v = f2i + f1t[t];
                v = fmaxf(v, 0.2f * v);
                float e = ((mi >> j) & 1ull) ? v : -9e15f;
                float p = __expf(e - mjt[t]) * rjt[t];
                pf[t] = (__bf16)p;
            }
#pragma unroll
            for (int nt = 0; nt < 4; nt++)
                acc2[mt][nt] = __builtin_amdgcn_mfma_f32_16x16x32_bf16(
                    pf, hb[nt], acc2[mt][nt], 0, 0, 0);
        }
    }
    __syncthreads();   // hT reads done before overwrite

    // ---- ELU + write hout into buf, then coalesced store ----
#pragma unroll
    for (int mt = 0; mt < 4; mt++)
#pragma unroll
        for (int nt = 0; nt < 4; nt++)
#pragma unroll
            for (int r = 0; r < 4; r++) {
                float v = acc2[mt][nt][r];
                v = v > 0.f ? v : __expf(v) - 1.f;
                buf[(mt * 16 + lq * 4 + r) * S_IN + wave * 64 + nt * 16 + lr] = f2bf(v);
            }
    __syncthreads();
    u16* dst = hx_out + (size_t)b * N_ * HID_;
    for (int idx = tid; idx < N_ * 64; idx += 512) {
        int r = idx >> 6, q = idx & 63;
        *(uint4*)(dst + r * HID_ + q * 8) = *(const uint4*)&buf[r * S_IN + q * 8];
    }
}

// ---------------------------------------------------------------------------
// pooled[b,:] = sum_n hx[b,n,:]; logits = pooled @ W_out + b_out; log_softmax
// ---------------------------------------------------------------------------
__global__ __launch_bounds__(256) void pool_out(
    const u16* __restrict__ hx, const float* __restrict__ Wout,
    const float* __restrict__ bout, float* __restrict__ out)
{
    __shared__ float pooled[HID_];
    __shared__ float lg[3];
    const int tid = threadIdx.x;
    const int b = blockIdx.x;
    const u16* hb = hx + (size_t)b * N_ * HID_;
    for (int f = tid; f < HID_; f += 256) {
        float s = 0.f;
        for (int n = 0; n < N_; n++) s += bf2f(hb[n * HID_ + f]);
        pooled[f] = s;
    }
    __syncthreads();
    if (tid < 192) {
        int c = tid >> 6, lane = tid & 63;
        float p = 0.f;
        for (int k = lane; k < HID_; k += 64) p += pooled[k] * Wout[k * 3 + c];
        for (int off = 32; off > 0; off >>= 1) p += __shfl_down(p, off, 64);
        if (lane == 0) lg[c] = p + bout[c];
    }
    __syncthreads();
    if (tid == 0) {
        float l0 = lg[0], l1 = lg[1], l2 = lg[2];
        float m = fmaxf(l0, fmaxf(l1, l2));
        float s = __expf(l0 - m) + __expf(l1 - m) + __expf(l2 - m);
        float ls = m + logf(s);
        out[b * 3 + 0] = l0 - ls;
        out[b * 3 + 1] = l1 - ls;
        out[b * 3 + 2] = l2 - ls;
    }
}

// ---------------------------------------------------------------------------
extern "C" void kernel_launch(void* const* d_in, const int* in_sizes, int n_in,
                              void* d_out, int out_size, void* d_ws, size_t ws_size,
                              hipStream_t stream)
{
    const float* x   = (const float*)d_in[0];
    const int*   adj = (const int*)d_in[1];
    const float* bng = (const float*)d_in[2];
    const float* bnb = (const float*)d_in[3];
    const float* bnm = (const float*)d_in[4];
    const float* bnv = (const float*)d_in[5];
    const float* Wm  = (const float*)d_in[6];
    const float* bm  = (const float*)d_in[7];
    const float* Wg  = (const float*)d_in[8];
    const float* ag  = (const float*)d_in[9];
    const float* Wo  = (const float*)d_in[10];
    const float* bo  = (const float*)d_in[11];
    float* out = (float*)d_out;

    // ws layout: masks (u64) | xb | hx | wmlp_t | wgat_t   (~165 MB total)
    uint64_t* masks = (uint64_t*)d_ws;
    u16* xb     = (u16*)(masks + (size_t)B_ * 64);
    u16* hx     = xb + (size_t)M_ * FIN_;
    u16* wmlp_t = hx + (size_t)M_ * HID_;
    u16* wgat_t = wmlp_t + (size_t)HID_ * FIN_;

    bn_cast<<<(M_ * (FIN_ / 4) + 255) / 256, 256, 0, stream>>>(x, bng, bnb, bnm, bnv, xb);

    int rep_total = HID_ * FIN_ + LAYERS_ * HID_ * HID_;
    repack_w<<<(rep_total + 255) / 256, 256, 0, stream>>>(Wm, Wg, wmlp_t, wgat_t);

    build_masks<<<B_, 256, 0, stream>>>(adj, masks);

    // MLP: hx = xb @ W_mlp + b_mlp
    gemm_mfma<<<(M_ / 128) * 4, 256, 0, stream>>>(xb, wmlp_t, bm, hx, FIN_, FIN_);

    for (int l = 0; l < LAYERS_; l++) {
        gat_layer<<<B_, 512, 0, stream>>>(
            hx, hx, wgat_t + (size_t)l * HID_ * HID_,
            ag + (size_t)l * HEADS_ * 2 * FOUT_, masks);
    }
    pool_out<<<B_, 256, 0, stream>>>(hx, Wo, bo, out);
}